// Round 9
// baseline (335.273 us; speedup 1.0000x reference)
//
#include <hip/hip_runtime.h>
#include <cstdint>

#define H_ 128
#define W_ 128
#define HW 16384

typedef _Float16 f16x8 __attribute__((ext_vector_type(8)));
typedef _Float16 f16x4 __attribute__((ext_vector_type(4)));
typedef _Float16 f16x2 __attribute__((ext_vector_type(2)));
typedef float f32x4 __attribute__((ext_vector_type(4)));

// ---------------------------------------------------------------------------
// All weight preps + input transposes in ONE launch (branch ladder on blockIdx).
// Deform weight layout (NEW): wp2 chunk ((g*3+s)*4+q)*64 + co, 8 ch elements —
// lane-contiguous for the deform aF loads (64 lanes -> 16 lines, was 64).
// ---------------------------------------------------------------------------
__global__ __launch_bounds__(256)
void prep_all(const float* __restrict__ wd, const float* __restrict__ w1,
              const float* __restrict__ w2, const float* __restrict__ w3,
              const float* __restrict__ w4, const float* __restrict__ x,
              const float* __restrict__ ef,
              _Float16* __restrict__ wp, _Float16* __restrict__ A1,
              _Float16* __restrict__ A2, _Float16* __restrict__ A3,
              _Float16* __restrict__ A4, _Float16* __restrict__ xt,
              _Float16* __restrict__ ef_t) {
    __shared__ __align__(16) _Float16 t[128 * 200];
    const int bx  = blockIdx.x;
    const int tid = threadIdx.x;
    if (bx < 384) {                          // deform weight -> wp2 (see above)
        int i = bx * 256 + tid;              // 0..98303
        int e = i & 7;
        int chunk = i >> 3;                  // 0..12287
        int o = chunk & 63;
        int tq = chunk >> 6;
        int q = tq & 3;
        int u = tq >> 2;                     // g*3+s, 0..47
        int s = u % 3;
        int g = u / 3;
        int k = s * 4 + q;
        float v = 0.f;
        if (k < 9) v = wd[(o * 128 + g * 8 + e) * 9 + k];
        wp[i] = (_Float16)v;
    } else if (bx < 2256) {                  // conv A layouts
        const float* w; _Float16* Ap; int CIN, COUT, COpad, base;
        if (bx < 816)       { w = w1; Ap = A1; CIN = 192; COUT = 64;  COpad = 64;  base = 384; }
        else if (bx < 960)  { w = w2; Ap = A2; CIN = 64;  COUT = 64;  COpad = 64;  base = 816; }
        else if (bx < 1104) { w = w3; Ap = A3; CIN = 64;  COUT = 64;  COpad = 64;  base = 960; }
        else                { w = w4; Ap = A4; CIN = 64;  COUT = 432; COpad = 512; base = 1104; }
        int i = (bx - base) * 256 + tid;
        int kb = i / (COpad * 8);
        int rem = i - kb * (COpad * 8);
        int co = rem >> 3, j = rem & 7;
        int k = kb * 8 + j;
        int s = k / CIN;
        int ci = k - s * CIN;
        int kh = s / 3, kw = s % 3;
        float v = (co < COUT) ? w[((size_t)co * CIN + ci) * 9 + kh * 3 + kw] : 0.f;
        Ap[i] = (_Float16)v;
    } else if (bx < 6352) {                  // x -> xt[b][g][px][c8] fp16
        int i = (bx - 2256) * 256 + tid;
        int px = i & 16383;
        int g  = (i >> 14) & 15;
        int b  = i >> 18;
        const float* xp = x + ((size_t)(b * 128 + g * 8) * HW) + px;
        f16x8 v;
        #pragma unroll
        for (int c = 0; c < 8; ++c) v[c] = (_Float16)xp[c * HW];
        *(f16x8*)(xt + (size_t)i * 8) = v;
    } else {                                 // extra_feat NCHW -> NHWC fp16
        int bb = bx - 6352;
        int b = bb >> 7, h = bb & 127;
        for (int i = tid; i < 192 * 128; i += 256) {
            int c = i >> 7, w = i & 127;
            t[w * 200 + c] = (_Float16)ef[((size_t)(b * 192 + c) * 128 + h) * 128 + w];
        }
        __syncthreads();
        _Float16* ob = ef_t + ((size_t)(b * 128 + h) * 128) * 192;
        for (int i = tid; i < 128 * 24; i += 256) {
            int px = i / 24, c8 = i % 24;
            *(f16x8*)(ob + px * 192 + c8 * 8) = *(const f16x8*)(t + px * 200 + c8 * 8);
        }
    }
}

// ---------------------------------------------------------------------------
// MFMA implicit-GEMM 3x3 conv, pad 1. 64-px half-row tiles (25.3 KB LDS).
// STRAIGHT-LINE structure only: stage -> barrier -> compute -> epilogue,
// cout groups via blockIdx.y. conv4: MT=4/NT=4 (r8-verified).
// ACT 1 = lrelu -> NHWC fp16. ACT 2 = conv4 epilogue (offsets+mask).
// ---------------------------------------------------------------------------
template<int CIN_T, int COUT_T, int COpad_T, int NWM, int NWN, int MT, int NT,
         int ACT, int MINW>
__global__ __launch_bounds__(256, MINW)
void conv_mfma2(const _Float16* __restrict__ in, const _Float16* __restrict__ Ap,
                const float* __restrict__ bias, void* __restrict__ outp,
                _Float16* __restrict__ mskp) {
    constexpr int PX = 64;
    static_assert(NWM * NWN == 4 && NWN * NT * 16 == PX, "tiling");
    constexpr int TW  = PX + 2;                  // 66
    constexpr int CPC = CIN_T / 8;
    constexpr int NKH = (CIN_T == 64) ? 3 : 1;
    constexpr int NST = 3 / NKH;
    constexpr int TC  = NKH * TW * CPC;          // f16x8 chunks per stage
    constexpr int COg = NWM * MT * 16;
    __shared__ __align__(16) _Float16 lds[TC * 8];

    const int tid  = threadIdx.x;
    const int bxr  = (blockIdx.x & 7) * 128 + (blockIdx.x >> 3);
    const int ns   = bxr & 1;
    const int bh   = bxr >> 1;
    const int b    = bh >> 7;
    const int h    = bh & 127;
    const int cogB = blockIdx.y * COg;
    const int wv   = tid >> 6;
    const int wv_m = wv / NWN;
    const int wv_n = wv - wv_m * NWN;
    const int lane = tid & 63;
    const int quad = lane >> 4;
    const int l16  = lane & 15;
    const int w0g  = ns * PX;

    f32x4 acc[MT][NT];
    #pragma unroll
    for (int mt = 0; mt < MT; ++mt)
        #pragma unroll
        for (int nt = 0; nt < NT; ++nt) acc[mt][nt] = (f32x4){0.f, 0.f, 0.f, 0.f};

    const _Float16* inb = in + (size_t)b * (HW * CIN_T);

    auto stage = [&](int s) {
        for (int i = tid; i < TC; i += 256) {
            int kh_l = i / (TW * CPC);
            int r2   = i - kh_l * (TW * CPC);
            int wp_  = r2 / CPC;
            int c8   = r2 - wp_ * CPC;
            int kh   = s * NKH + kh_l;
            int hh   = h - 1 + kh;
            int w    = w0g + wp_ - 1;
            f16x8 v = (f16x8){0, 0, 0, 0, 0, 0, 0, 0};
            if ((unsigned)hh < 128u && (unsigned)w < 128u)
                v = *(const f16x8*)(inb + (hh * 128 + w) * CIN_T + c8 * 8);
            int slot = (c8 & ~7) | ((c8 & 7) ^ (wp_ & 7));
            ((f16x8*)lds)[(kh_l * TW + wp_) * CPC + slot] = v;
        }
    };

    auto compute = [&](int s) {
        #pragma unroll
        for (int kh_l = 0; kh_l < NKH; ++kh_l) {
            const int kh = s * NKH + kh_l;
            #pragma unroll
            for (int kwi = 0; kwi < 3; ++kwi) {
                #pragma unroll
                for (int ci32 = 0; ci32 < CIN_T / 32; ++ci32) {
                    const int kb0 = (kh * 3 + kwi) * CPC + ci32 * 4;
                    f16x8 aF[MT];
                    #pragma unroll
                    for (int mt = 0; mt < MT; ++mt) {
                        int co_m = cogB + (wv_m * MT + mt) * 16 + l16;
                        aF[mt] = *(const f16x8*)(Ap + ((size_t)(kb0 + quad) * COpad_T + co_m) * 8);
                    }
                    const int c8v = ci32 * 4 + quad;
                    #pragma unroll
                    for (int nt = 0; nt < NT; ++nt) {
                        int n  = (wv_n * NT + nt) * 16 + l16;
                        int wq = n + kwi;
                        int slot = (c8v & ~7) | ((c8v & 7) ^ (wq & 7));
                        f16x8 bF = ((const f16x8*)lds)[(kh_l * TW + wq) * CPC + slot];
                        #pragma unroll
                        for (int mt = 0; mt < MT; ++mt)
                            acc[mt][nt] = __builtin_amdgcn_mfma_f32_16x16x32_f16(aF[mt], bF, acc[mt][nt], 0, 0, 0);
                    }
                }
            }
        }
    };

    #pragma unroll 1
    for (int s = 0; s < NST; ++s) {
        __syncthreads();
        stage(s);
        __syncthreads();
        compute(s);
    }

    if constexpr (ACT == 1) {
        _Float16* ob = (_Float16*)outp + ((size_t)((b * 128 + h) * 128) + w0g) * 64;
        #pragma unroll
        for (int mt = 0; mt < MT; ++mt) {
            int co_b = (wv_m * MT + mt) * 16 + quad * 4;
            #pragma unroll
            for (int nt = 0; nt < NT; ++nt) {
                int px = (wv_n * NT + nt) * 16 + l16;
                f16x4 sv;
                #pragma unroll
                for (int r = 0; r < 4; ++r) {
                    float v = acc[mt][nt][r] + bias[co_b + r];
                    v = v > 0.f ? v : 0.1f * v;
                    sv[r] = (_Float16)v;
                }
                *(f16x4*)(ob + px * 64 + co_b) = sv;
            }
        }
    } else {
        _Float16* off2 = (_Float16*)outp;
        const int pxbase = h * 128 + w0g;
        #pragma unroll
        for (int mt = 0; mt < MT; ++mt) {
            int co_base = cogB + (wv_m * MT + mt) * 16 + quad * 4;   // even
            #pragma unroll
            for (int r2 = 0; r2 < 2; ++r2) {
                int co0 = co_base + 2 * r2;
                if (co0 < 288) {             // offset pair (dy co0, dx co0+1)
                    int g = co0 / 18;
                    int k = (co0 - g * 18) >> 1;
                    float bv0 = bias[co0], bv1 = bias[co0 + 1];
                    #pragma unroll
                    for (int nt = 0; nt < NT; ++nt) {
                        int px = (wv_n * NT + nt) * 16 + l16;
                        float v0 = acc[mt][nt][2 * r2]     + bv0;
                        float v1 = acc[mt][nt][2 * r2 + 1] + bv1;
                        float e0 = __expf(2.f * v0);
                        float e1 = __expf(2.f * v1);
                        f16x2 ov;
                        ov[0] = (_Float16)(10.f * (1.f - 2.f / (e0 + 1.f)));
                        ov[1] = (_Float16)(10.f * (1.f - 2.f / (e1 + 1.f)));
                        *(f16x2*)(off2 + (((size_t)(b * 16 + g) * 9 + k) * HW + pxbase + px) * 2) = ov;
                    }
                } else if (co0 < 432) {      // two mask channels
                    #pragma unroll
                    for (int j = 0; j < 2; ++j) {
                        int co = co0 + j;
                        int mm = co - 288;
                        int g = mm / 9;
                        int k = mm - g * 9;
                        float bv = bias[co];
                        #pragma unroll
                        for (int nt = 0; nt < NT; ++nt) {
                            int px = (wv_n * NT + nt) * 16 + l16;
                            float v = acc[mt][nt][2 * r2 + j] + bv;
                            v = 1.f / (1.f + __expf(-v));
                            mskp[((size_t)(b * 16 + g) * 9 + k) * HW + pxbase + px] = (_Float16)v;
                        }
                    }
                }
            }
        }
    }
}

// ---------------------------------------------------------------------------
// FUSED deformable conv, LDS-window gather. r6/r7 nulls proved the limiter
// is scattered cache-line THROUGHPUT (~1 line/cyc/CU TA): 2304 gather lines
// + 768 strided aF lines per block-group == the measured 11.2k cyc/round.
// Offsets are bounded (|d| <= 10), so each group's gather support is a fixed
// 24-row x 89-col window (34 KB): stage it COALESCED into LDS (~530 lines),
// gather via ds_read_b128 (bank-parallel). aF now lane-contiguous (wp2).
// Schedule: gather(g) -> bar -> [stage_win(g+1) || MFMA(g)] -> bar.
// Clamp-at-stage makes unclamped gather index arithmetic exact.
// ---------------------------------------------------------------------------
__global__ __launch_bounds__(256, 3)
void deform_fused(const _Float16* __restrict__ xt, const _Float16* __restrict__ off2,
                  const _Float16* __restrict__ msk, const _Float16* __restrict__ wp,
                  const float* __restrict__ bias, float* __restrict__ out) {
    constexpr int WROW = 24, WCOL = 89;             // rows hrow-11..+12, cols w0-11..+77
    __shared__ __align__(16) char lds_all[WROW * WCOL * 16 + 64 * 256];  // 50,560 B
    char* winb = lds_all;
    char* vb   = lds_all + WROW * WCOL * 16;

    const int tid  = threadIdx.x;
    const int bx   = (blockIdx.x & 7) * 128 + (blockIdx.x >> 3);
    const int ns   = bx & 1;
    const int bh   = bx >> 1;
    const int b    = bh >> 7;
    const int hrow = bh & 127;
    const int wv   = tid >> 6;
    const int lane = tid & 63;
    const int quad = lane >> 4;
    const int l16  = lane & 15;

    const int pxl   = tid & 63;        // local px (V row)
    const int kq    = tid >> 6;        // k-quarter (wave-uniform)
    const int wglob = ns * 64 + pxl;
    const int pxg   = hrow * 128 + wglob;
    const int rbase = hrow - 11;
    const int cbase = ns * 64 - 11;

    {   // zero V once: swizzled chunks from k in 9..11 are MFMA-read, never written
        f32x4 z = (f32x4){0.f, 0.f, 0.f, 0.f};
        for (int i = tid; i < 1024; i += 256) ((f32x4*)vb)[i] = z;
    }

    const _Float16* o2b = off2 + (size_t)b * 16 * 9 * HW * 2;
    const _Float16* mb  = msk  + (size_t)b * 16 * 9 * HW;

    f32x4 acc[4];
    #pragma unroll
    for (int nt = 0; nt < 4; ++nt) acc[nt] = (f32x4){0.f, 0.f, 0.f, 0.f};

    auto stage_win = [&](int gl) {
        const _Float16* xg = xt + ((size_t)(b * 16 + gl) * HW) * 8;
        #pragma unroll
        for (int it = 0; it < 9; ++it) {
            int i = tid + it * 256;
            if (i < WROW * WCOL) {
                int r = i / WCOL;
                int c = i - r * WCOL;
                int ry = min(max(rbase + r, 0), 127);
                int cx = min(max(cbase + c, 0), 127);
                *(f16x8*)(winb + i * 16) = *(const f16x8*)(xg + (ry * 128 + cx) * 8);
            }
        }
    };

    auto gather = [&](const f16x2* od, const _Float16* m) {
        #pragma unroll
        for (int i = 0; i < 3; ++i) {
            int k = kq + 4 * i;
            if (k < 9) {
                float dy = (float)od[i][0];
                float dx = (float)od[i][1];
                float mm = (float)m[i];
                float py  = (float)(hrow - 1 + k / 3) + dy;
                float pxf = (float)(wglob - 1 + k % 3) + dx;
                float y0f = floorf(py), x0f = floorf(pxf);
                float ly = py - y0f, lx = pxf - x0f;
                int y0 = (int)y0f, x0 = (int)x0f;
                int y1 = y0 + 1,  x1 = x0 + 1;
                float vy0 = ((unsigned)y0 < 128u) ? 1.f : 0.f;
                float vy1 = ((unsigned)y1 < 128u) ? 1.f : 0.f;
                float vx0 = ((unsigned)x0 < 128u) ? 1.f : 0.f;
                float vx1 = ((unsigned)x1 < 128u) ? 1.f : 0.f;
                _Float16 h00 = (_Float16)((1.f - ly) * (1.f - lx) * vy0 * vx0 * mm);
                _Float16 h01 = (_Float16)((1.f - ly) * lx         * vy0 * vx1 * mm);
                _Float16 h10 = (_Float16)(ly * (1.f - lx)         * vy1 * vx0 * mm);
                _Float16 h11 = (_Float16)(ly * lx                 * vy1 * vx1 * mm);
                // unclamped window indices (stage-side clamp == gather clamp)
                int ci = (y0 - rbase) * WCOL + (x0 - cbase);     // 0..2110
                f16x8 c00 = *(const f16x8*)(winb + ci * 16);
                f16x8 c01 = *(const f16x8*)(winb + ci * 16 + 16);
                f16x8 c10 = *(const f16x8*)(winb + (ci + WCOL) * 16);
                f16x8 c11 = *(const f16x8*)(winb + (ci + WCOL) * 16 + 16);
                f16x8 vv = c00 * h00 + c01 * h01 + c10 * h10 + c11 * h11;  // v_pk_fma_f16
                *(f16x8*)(vb + pxl * 256 + ((k ^ (pxl & 15)) << 4)) = vv;
            }
        }
    };

    // prologue: offsets(0) + window(0)
    f16x2 od_c[3]; _Float16 m_c[3];
    #pragma unroll
    for (int i = 0; i < 3; ++i) {
        od_c[i] = (f16x2){0, 0}; m_c[i] = (_Float16)0.f;
        int k = kq + 4 * i;
        if (k < 9) {
            od_c[i] = *(const f16x2*)(o2b + ((size_t)k * HW + pxg) * 2);
            m_c[i]  = mb[(size_t)k * HW + pxg];
        }
    }
    stage_win(0);
    __syncthreads();

    #pragma unroll 1
    for (int gl = 0; gl < 16; ++gl) {
        // prefetch offsets/masks for gl+1 (consumed next iteration)
        f16x2 od_n[3]; _Float16 m_n[3];
        #pragma unroll
        for (int i = 0; i < 3; ++i) { od_n[i] = (f16x2){0, 0}; m_n[i] = (_Float16)0.f; }
        if (gl < 15) {
            #pragma unroll
            for (int i = 0; i < 3; ++i) {
                int k = kq + 4 * i;
                if (k < 9) {
                    od_n[i] = *(const f16x2*)(o2b + ((size_t)((gl + 1) * 9 + k) * HW + pxg) * 2);
                    m_n[i]  = mb[(size_t)((gl + 1) * 9 + k) * HW + pxg];
                }
            }
        }

        gather(od_c, m_c);             // LDS window reads -> V writes
        __syncthreads();               // window free, V ready

        if (gl < 15) stage_win(gl + 1);            // coalesced, overlaps MFMA

        f16x8 aF[3];
        #pragma unroll
        for (int s = 0; s < 3; ++s)
            aF[s] = *(const f16x8*)(wp + (size_t)((((gl * 3 + s) * 4 + quad) * 64) + wv * 16 + l16) * 8);

        #pragma unroll
        for (int nt = 0; nt < 4; ++nt) {
            int row = nt * 16 + l16;
            int sw  = row & 15;
            #pragma unroll
            for (int s = 0; s < 3; ++s) {
                f16x8 bF = *(const f16x8*)(vb + row * 256 + (((s << 2) + quad) ^ sw) * 16);
                acc[nt] = __builtin_amdgcn_mfma_f32_16x16x32_f16(aF[s], bF, acc[nt], 0, 0, 0);
            }
        }
        __syncthreads();               // window(gl+1) staged; V read done

        #pragma unroll
        for (int i = 0; i < 3; ++i) { od_c[i] = od_n[i]; m_c[i] = m_n[i]; }
    }

    // ---- epilogue: transpose 64co x 64px through LDS, coalesced fp32 stores
    float* vf = (float*)lds_all;       // 16 KB
    #pragma unroll
    for (int r = 0; r < 4; ++r) {
        int o = wv * 16 + quad * 4 + r;
        #pragma unroll
        for (int nt = 0; nt < 4; ++nt) {
            int col = nt ^ quad;
            vf[o * 64 + col * 16 + l16] = acc[nt][r];
        }
    }
    __syncthreads();
    float* ob = out + ((size_t)(b * 64)) * HW + hrow * 128 + ns * 64;
    #pragma unroll
    for (int it = 0; it < 4; ++it) {
        int slot = tid + it * 256;
        int o    = slot >> 4;
        int p4   = slot & 15;
        int col  = (p4 >> 2) ^ ((o >> 2) & 3);
        f32x4 v = *(const f32x4*)(vf + o * 64 + col * 16 + (p4 & 3) * 4);
        float bv = bias[o];
        float4 sv = make_float4(v[0] + bv, v[1] + bv, v[2] + bv, v[3] + bv);
        *(float4*)(ob + (size_t)o * HW + p4 * 4) = sv;
    }
}

// ---------------------------------------------------------------------------
extern "C" void kernel_launch(void* const* d_in, const int* in_sizes, int n_in,
                              void* d_out, int out_size, void* d_ws, size_t ws_size,
                              hipStream_t stream) {
    const float* x  = (const float*)d_in[0];
    const float* ef = (const float*)d_in[1];
    const float* w1 = (const float*)d_in[2];
    const float* b1 = (const float*)d_in[3];
    const float* w2 = (const float*)d_in[4];
    const float* b2 = (const float*)d_in[5];
    const float* w3 = (const float*)d_in[6];
    const float* b3 = (const float*)d_in[7];
    const float* w4 = (const float*)d_in[8];
    const float* b4 = (const float*)d_in[9];
    const float* wd = (const float*)d_in[10];
    const float* bd = (const float*)d_in[11];
    float* out = (float*)d_out;

    char* ws = (char*)d_ws;
    _Float16* ef_t = (_Float16*)(ws);                     // 25,165,824 B
    _Float16* tA   = (_Float16*)(ws + 25165824);          //  8,388,608 B
    _Float16* tB   = (_Float16*)(ws + 33554432);          //  8,388,608 B
    _Float16* off2 = (_Float16*)(ws + 41943040);          // 37,748,736 B
    _Float16* mskb = (_Float16*)(ws + 79691776);          // 18,874,368 B
    _Float16* wpd  = (_Float16*)(ws + 98566144);          //    196,608 B
    _Float16* A1   = (_Float16*)(ws + 98762752);          //    221,184 B
    _Float16* A2   = (_Float16*)(ws + 98983936);          //     73,728 B
    _Float16* A3   = (_Float16*)(ws + 99057664);          //     73,728 B
    _Float16* A4   = (_Float16*)(ws + 99131392);          //    589,824 B
    _Float16* xtb  = (_Float16*)(ws + 99721216);          // 16,777,216 B -> ends 116,498,432

    prep_all<<<6864, 256, 0, stream>>>(wd, w1, w2, w3, w4, x, ef,
                                       wpd, A1, A2, A3, A4, xtb, ef_t);

    //            CIN  COUT COpad NWM NWN MT NT ACT MINW
    conv_mfma2<192,  64,  64,  2,  2, 2, 2, 1, 4><<<dim3(1024, 1), 256, 0, stream>>>(ef_t, A1, b1, tA, nullptr);
    conv_mfma2< 64,  64,  64,  2,  2, 2, 2, 1, 4><<<dim3(1024, 1), 256, 0, stream>>>(tA, A2, b2, tB, nullptr);
    conv_mfma2< 64,  64,  64,  2,  2, 2, 2, 1, 4><<<dim3(1024, 1), 256, 0, stream>>>(tB, A3, b3, tA, nullptr);
    conv_mfma2< 64, 432, 512,  4,  1, 4, 4, 2, 3><<<dim3(1024, 2), 256, 0, stream>>>(tA, A4, b4, off2, mskb);

    deform_fused<<<1024, 256, 0, stream>>>(xtb, off2, mskb, wpd, bd, out);
}

// Round 10
// 316.553 us; speedup vs baseline: 1.0591x; 1.0591x over previous
//
#include <hip/hip_runtime.h>
#include <cstdint>

#define H_ 128
#define W_ 128
#define HW 16384

typedef _Float16 f16x8 __attribute__((ext_vector_type(8)));
typedef _Float16 f16x4 __attribute__((ext_vector_type(4)));
typedef _Float16 f16x2 __attribute__((ext_vector_type(2)));
typedef float f32x4 __attribute__((ext_vector_type(4)));

// ---------------------------------------------------------------------------
// All weight preps + input transposes in ONE launch (branch ladder on blockIdx).
// Deform weight layout wp2: chunk ((g*3+s)*4+q)*64 + co, 8 ch elements —
// lane-contiguous for the deform aF loads (64 lanes -> 16 lines, was 64/load).
// ---------------------------------------------------------------------------
__global__ __launch_bounds__(256)
void prep_all(const float* __restrict__ wd, const float* __restrict__ w1,
              const float* __restrict__ w2, const float* __restrict__ w3,
              const float* __restrict__ w4, const float* __restrict__ x,
              const float* __restrict__ ef,
              _Float16* __restrict__ wp, _Float16* __restrict__ A1,
              _Float16* __restrict__ A2, _Float16* __restrict__ A3,
              _Float16* __restrict__ A4, _Float16* __restrict__ xt,
              _Float16* __restrict__ ef_t) {
    __shared__ __align__(16) _Float16 t[128 * 200];
    const int bx  = blockIdx.x;
    const int tid = threadIdx.x;
    if (bx < 384) {                          // deform weight -> wp2 (see above)
        int i = bx * 256 + tid;              // 0..98303
        int e = i & 7;
        int chunk = i >> 3;                  // 0..12287
        int o = chunk & 63;
        int tq = chunk >> 6;
        int q = tq & 3;
        int u = tq >> 2;                     // g*3+s, 0..47
        int s = u % 3;
        int g = u / 3;
        int k = s * 4 + q;
        float v = 0.f;
        if (k < 9) v = wd[(o * 128 + g * 8 + e) * 9 + k];
        wp[i] = (_Float16)v;
    } else if (bx < 2256) {                  // conv A layouts
        const float* w; _Float16* Ap; int CIN, COUT, COpad, base;
        if (bx < 816)       { w = w1; Ap = A1; CIN = 192; COUT = 64;  COpad = 64;  base = 384; }
        else if (bx < 960)  { w = w2; Ap = A2; CIN = 64;  COUT = 64;  COpad = 64;  base = 816; }
        else if (bx < 1104) { w = w3; Ap = A3; CIN = 64;  COUT = 64;  COpad = 64;  base = 960; }
        else                { w = w4; Ap = A4; CIN = 64;  COUT = 432; COpad = 512; base = 1104; }
        int i = (bx - base) * 256 + tid;
        int kb = i / (COpad * 8);
        int rem = i - kb * (COpad * 8);
        int co = rem >> 3, j = rem & 7;
        int k = kb * 8 + j;
        int s = k / CIN;
        int ci = k - s * CIN;
        int kh = s / 3, kw = s % 3;
        float v = (co < COUT) ? w[((size_t)co * CIN + ci) * 9 + kh * 3 + kw] : 0.f;
        Ap[i] = (_Float16)v;
    } else if (bx < 6352) {                  // x -> xt[b][g][px][c8] fp16
        int i = (bx - 2256) * 256 + tid;
        int px = i & 16383;
        int g  = (i >> 14) & 15;
        int b  = i >> 18;
        const float* xp = x + ((size_t)(b * 128 + g * 8) * HW) + px;
        f16x8 v;
        #pragma unroll
        for (int c = 0; c < 8; ++c) v[c] = (_Float16)xp[c * HW];
        *(f16x8*)(xt + (size_t)i * 8) = v;
    } else {                                 // extra_feat NCHW -> NHWC fp16
        int bb = bx - 6352;
        int b = bb >> 7, h = bb & 127;
        for (int i = tid; i < 192 * 128; i += 256) {
            int c = i >> 7, w = i & 127;
            t[w * 200 + c] = (_Float16)ef[((size_t)(b * 192 + c) * 128 + h) * 128 + w];
        }
        __syncthreads();
        _Float16* ob = ef_t + ((size_t)(b * 128 + h) * 128) * 192;
        for (int i = tid; i < 128 * 24; i += 256) {
            int px = i / 24, c8 = i % 24;
            *(f16x8*)(ob + px * 192 + c8 * 8) = *(const f16x8*)(t + px * 200 + c8 * 8);
        }
    }
}

// ---------------------------------------------------------------------------
// MFMA implicit-GEMM 3x3 conv, pad 1. 64-px half-row tiles (25.3 KB LDS).
// STRAIGHT-LINE structure only: stage -> barrier -> compute -> epilogue,
// cout groups via blockIdx.y. conv4: MT=4/NT=4 (r8-verified).
// ACT 1 = lrelu -> NHWC fp16. ACT 2 = conv4 epilogue (offsets+mask).
// ---------------------------------------------------------------------------
template<int CIN_T, int COUT_T, int COpad_T, int NWM, int NWN, int MT, int NT,
         int ACT, int MINW>
__global__ __launch_bounds__(256, MINW)
void conv_mfma2(const _Float16* __restrict__ in, const _Float16* __restrict__ Ap,
                const float* __restrict__ bias, void* __restrict__ outp,
                _Float16* __restrict__ mskp) {
    constexpr int PX = 64;
    static_assert(NWM * NWN == 4 && NWN * NT * 16 == PX, "tiling");
    constexpr int TW  = PX + 2;                  // 66
    constexpr int CPC = CIN_T / 8;
    constexpr int NKH = (CIN_T == 64) ? 3 : 1;
    constexpr int NST = 3 / NKH;
    constexpr int TC  = NKH * TW * CPC;          // f16x8 chunks per stage
    constexpr int COg = NWM * MT * 16;
    __shared__ __align__(16) _Float16 lds[TC * 8];

    const int tid  = threadIdx.x;
    const int bxr  = (blockIdx.x & 7) * 128 + (blockIdx.x >> 3);
    const int ns   = bxr & 1;
    const int bh   = bxr >> 1;
    const int b    = bh >> 7;
    const int h    = bh & 127;
    const int cogB = blockIdx.y * COg;
    const int wv   = tid >> 6;
    const int wv_m = wv / NWN;
    const int wv_n = wv - wv_m * NWN;
    const int lane = tid & 63;
    const int quad = lane >> 4;
    const int l16  = lane & 15;
    const int w0g  = ns * PX;

    f32x4 acc[MT][NT];
    #pragma unroll
    for (int mt = 0; mt < MT; ++mt)
        #pragma unroll
        for (int nt = 0; nt < NT; ++nt) acc[mt][nt] = (f32x4){0.f, 0.f, 0.f, 0.f};

    const _Float16* inb = in + (size_t)b * (HW * CIN_T);

    auto stage = [&](int s) {
        for (int i = tid; i < TC; i += 256) {
            int kh_l = i / (TW * CPC);
            int r2   = i - kh_l * (TW * CPC);
            int wp_  = r2 / CPC;
            int c8   = r2 - wp_ * CPC;
            int kh   = s * NKH + kh_l;
            int hh   = h - 1 + kh;
            int w    = w0g + wp_ - 1;
            f16x8 v = (f16x8){0, 0, 0, 0, 0, 0, 0, 0};
            if ((unsigned)hh < 128u && (unsigned)w < 128u)
                v = *(const f16x8*)(inb + (hh * 128 + w) * CIN_T + c8 * 8);
            int slot = (c8 & ~7) | ((c8 & 7) ^ (wp_ & 7));
            ((f16x8*)lds)[(kh_l * TW + wp_) * CPC + slot] = v;
        }
    };

    auto compute = [&](int s) {
        #pragma unroll
        for (int kh_l = 0; kh_l < NKH; ++kh_l) {
            const int kh = s * NKH + kh_l;
            #pragma unroll
            for (int kwi = 0; kwi < 3; ++kwi) {
                #pragma unroll
                for (int ci32 = 0; ci32 < CIN_T / 32; ++ci32) {
                    const int kb0 = (kh * 3 + kwi) * CPC + ci32 * 4;
                    f16x8 aF[MT];
                    #pragma unroll
                    for (int mt = 0; mt < MT; ++mt) {
                        int co_m = cogB + (wv_m * MT + mt) * 16 + l16;
                        aF[mt] = *(const f16x8*)(Ap + ((size_t)(kb0 + quad) * COpad_T + co_m) * 8);
                    }
                    const int c8v = ci32 * 4 + quad;
                    #pragma unroll
                    for (int nt = 0; nt < NT; ++nt) {
                        int n  = (wv_n * NT + nt) * 16 + l16;
                        int wq = n + kwi;
                        int slot = (c8v & ~7) | ((c8v & 7) ^ (wq & 7));
                        f16x8 bF = ((const f16x8*)lds)[(kh_l * TW + wq) * CPC + slot];
                        #pragma unroll
                        for (int mt = 0; mt < MT; ++mt)
                            acc[mt][nt] = __builtin_amdgcn_mfma_f32_16x16x32_f16(aF[mt], bF, acc[mt][nt], 0, 0, 0);
                    }
                }
            }
        }
    };

    #pragma unroll 1
    for (int s = 0; s < NST; ++s) {
        __syncthreads();
        stage(s);
        __syncthreads();
        compute(s);
    }

    if constexpr (ACT == 1) {
        _Float16* ob = (_Float16*)outp + ((size_t)((b * 128 + h) * 128) + w0g) * 64;
        #pragma unroll
        for (int mt = 0; mt < MT; ++mt) {
            int co_b = (wv_m * MT + mt) * 16 + quad * 4;
            #pragma unroll
            for (int nt = 0; nt < NT; ++nt) {
                int px = (wv_n * NT + nt) * 16 + l16;
                f16x4 sv;
                #pragma unroll
                for (int r = 0; r < 4; ++r) {
                    float v = acc[mt][nt][r] + bias[co_b + r];
                    v = v > 0.f ? v : 0.1f * v;
                    sv[r] = (_Float16)v;
                }
                *(f16x4*)(ob + px * 64 + co_b) = sv;
            }
        }
    } else {
        _Float16* off2 = (_Float16*)outp;
        const int pxbase = h * 128 + w0g;
        #pragma unroll
        for (int mt = 0; mt < MT; ++mt) {
            int co_base = cogB + (wv_m * MT + mt) * 16 + quad * 4;   // even
            #pragma unroll
            for (int r2 = 0; r2 < 2; ++r2) {
                int co0 = co_base + 2 * r2;
                if (co0 < 288) {             // offset pair (dy co0, dx co0+1)
                    int g = co0 / 18;
                    int k = (co0 - g * 18) >> 1;
                    float bv0 = bias[co0], bv1 = bias[co0 + 1];
                    #pragma unroll
                    for (int nt = 0; nt < NT; ++nt) {
                        int px = (wv_n * NT + nt) * 16 + l16;
                        float v0 = acc[mt][nt][2 * r2]     + bv0;
                        float v1 = acc[mt][nt][2 * r2 + 1] + bv1;
                        float e0 = __expf(2.f * v0);
                        float e1 = __expf(2.f * v1);
                        f16x2 ov;
                        ov[0] = (_Float16)(10.f * (1.f - 2.f / (e0 + 1.f)));
                        ov[1] = (_Float16)(10.f * (1.f - 2.f / (e1 + 1.f)));
                        *(f16x2*)(off2 + (((size_t)(b * 16 + g) * 9 + k) * HW + pxbase + px) * 2) = ov;
                    }
                } else if (co0 < 432) {      // two mask channels
                    #pragma unroll
                    for (int j = 0; j < 2; ++j) {
                        int co = co0 + j;
                        int mm = co - 288;
                        int g = mm / 9;
                        int k = mm - g * 9;
                        float bv = bias[co];
                        #pragma unroll
                        for (int nt = 0; nt < NT; ++nt) {
                            int px = (wv_n * NT + nt) * 16 + l16;
                            float v = acc[mt][nt][2 * r2 + j] + bv;
                            v = 1.f / (1.f + __expf(-v));
                            mskp[((size_t)(b * 16 + g) * 9 + k) * HW + pxbase + px] = (_Float16)v;
                        }
                    }
                }
            }
        }
    }
}

// ---------------------------------------------------------------------------
// FUSED deformable conv: r8 structure (direct-global issue-all/finish-all
// gathers, 64-px, 0 bank conflicts, 32 KB LDS) + r9's wp2 lane-contiguous
// weight layout (aF: 768 -> 48 L2 lines per block-group; ~805 MB -> 50 MB of
// L2 line traffic per dispatch). r9's LDS-window gather is REVERTED (4.6M
// bank conflicts + occupancy loss made it a net regression).
// ---------------------------------------------------------------------------
__global__ __launch_bounds__(256, 4)
void deform_fused(const _Float16* __restrict__ xt, const _Float16* __restrict__ off2,
                  const _Float16* __restrict__ msk, const _Float16* __restrict__ wp,
                  const float* __restrict__ bias, float* __restrict__ out) {
    __shared__ __align__(16) char vlds[2 * 64 * 256];   // 32 KB, double-buffered
    const int tid  = threadIdx.x;
    const int bx   = (blockIdx.x & 7) * 128 + (blockIdx.x >> 3);
    const int ns   = bx & 1;
    const int bh   = bx >> 1;
    const int b    = bh >> 7;
    const int hrow = bh & 127;
    const int wv   = tid >> 6;
    const int lane = tid & 63;
    const int quad = lane >> 4;
    const int l16  = lane & 15;

    const int pxl   = tid & 63;        // local px (V row)
    const int kq    = tid >> 6;        // k-quarter (wave-uniform)
    const int wglob = ns * 64 + pxl;
    const int pxg   = hrow * 128 + wglob;

    {   // zero both buffers: swizzled chunks (9..11)^sw are never written
        f32x4 z = (f32x4){0.f, 0.f, 0.f, 0.f};
        for (int i = tid; i < 2048; i += 256) ((f32x4*)vlds)[i] = z;
    }
    __syncthreads();

    const _Float16* o2b = off2 + (size_t)b * 16 * 9 * HW * 2;
    const _Float16* mb  = msk  + (size_t)b * 16 * 9 * HW;

    f32x4 acc[4];
    #pragma unroll
    for (int nt = 0; nt < 4; ++nt) acc[nt] = (f32x4){0.f, 0.f, 0.f, 0.f};

    // LDS chunk byte offsets are group-invariant
    int ch[3];
    #pragma unroll
    for (int i = 0; i < 3; ++i) ch[i] = (((kq + 4 * i) ^ (pxl & 15)) << 4);

    // in-flight gather state (3 taps x 4 corners)
    f16x8 g00[3], g01[3], g10[3], g11[3];
    _Float16 h00[3], h01[3], h10[3], h11[3];

    // issue: compute all tap addrs+weights, fire all loads (no consumers here)
    auto issue = [&](int gl, const f16x2* od, const _Float16* m) {
        const _Float16* xg = xt + ((size_t)(b * 16 + gl) * HW) * 8;
        #pragma unroll
        for (int i = 0; i < 3; ++i) {
            int k = kq + 4 * i;
            if (k < 9) {
                float dy = (float)od[i][0];
                float dx = (float)od[i][1];
                float mm = (float)m[i];
                float py  = (float)(hrow - 1 + k / 3) + dy;
                float pxf = (float)(wglob - 1 + k % 3) + dx;
                float y0f = floorf(py), x0f = floorf(pxf);
                float ly = py - y0f, lx = pxf - x0f;
                int y0 = (int)y0f, x0 = (int)x0f;
                int y1 = y0 + 1,  x1 = x0 + 1;
                float vy0 = ((unsigned)y0 < 128u) ? 1.f : 0.f;
                float vy1 = ((unsigned)y1 < 128u) ? 1.f : 0.f;
                float vx0 = ((unsigned)x0 < 128u) ? 1.f : 0.f;
                float vx1 = ((unsigned)x1 < 128u) ? 1.f : 0.f;
                h00[i] = (_Float16)((1.f - ly) * (1.f - lx) * vy0 * vx0 * mm);
                h01[i] = (_Float16)((1.f - ly) * lx         * vy0 * vx1 * mm);
                h10[i] = (_Float16)(ly * (1.f - lx)         * vy1 * vx0 * mm);
                h11[i] = (_Float16)(ly * lx                 * vy1 * vx1 * mm);
                int yc0 = min(max(y0, 0), 127), yc1 = min(max(y1, 0), 127);
                int xc0 = min(max(x0, 0), 127), xc1 = min(max(x1, 0), 127);
                g00[i] = *(const f16x8*)(xg + (yc0 * W_ + xc0) * 8);
                g01[i] = *(const f16x8*)(xg + (yc0 * W_ + xc1) * 8);
                g10[i] = *(const f16x8*)(xg + (yc1 * W_ + xc0) * 8);
                g11[i] = *(const f16x8*)(xg + (yc1 * W_ + xc1) * 8);
            }
        }
    };

    // finish: lerp all taps, write V tile
    auto finish = [&](int gl) {
        char* vb = vlds + (gl & 1) * 16384;
        #pragma unroll
        for (int i = 0; i < 3; ++i) {
            int k = kq + 4 * i;
            if (k < 9) {
                f16x8 vv = g00[i] * h00[i] + g01[i] * h01[i]
                         + g10[i] * h10[i] + g11[i] * h11[i];   // v_pk_fma_f16
                *(f16x8*)(vb + pxl * 256 + ch[i]) = vv;
            }
        }
    };

    // prologue: offsets + gathers for group 0
    {
        f16x2 od0[3]; _Float16 m0[3];
        #pragma unroll
        for (int i = 0; i < 3; ++i) {
            od0[i] = (f16x2){0, 0}; m0[i] = (_Float16)0.f;
            int k = kq + 4 * i;
            if (k < 9) {
                od0[i] = *(const f16x2*)(o2b + ((size_t)k * HW + pxg) * 2);
                m0[i]  = mb[(size_t)k * HW + pxg];
            }
        }
        issue(0, od0, m0);
    }

    #pragma unroll 1
    for (int gl = 0; gl < 16; ++gl) {
        // prefetch offsets/masks for gl+1 (independent; long latency OK)
        f16x2 od_n[3]; _Float16 m_n[3];
        #pragma unroll
        for (int i = 0; i < 3; ++i) { od_n[i] = (f16x2){0, 0}; m_n[i] = (_Float16)0.f; }
        if (gl < 15) {
            #pragma unroll
            for (int i = 0; i < 3; ++i) {
                int k = kq + 4 * i;
                if (k < 9) {
                    od_n[i] = *(const f16x2*)(o2b + ((size_t)((gl + 1) * 9 + k) * HW + pxg) * 2);
                    m_n[i]  = mb[(size_t)((gl + 1) * 9 + k) * HW + pxg];
                }
            }
        }

        // weight fragments for this group — wp2 layout, lane-contiguous
        f16x8 aF[3];
        #pragma unroll
        for (int s = 0; s < 3; ++s)
            aF[s] = *(const f16x8*)(wp + (size_t)((((gl * 3 + s) * 4 + quad) * 64) + wv * 16 + l16) * 8);

        finish(gl);                    // wait gathers, lerp, write vb[gl&1]
        __syncthreads();

        if (gl < 15) issue(gl + 1, od_n, m_n);   // loads fly during MFMA

        char* vb = vlds + (gl & 1) * 16384;
        #pragma unroll
        for (int nt = 0; nt < 4; ++nt) {
            int row = nt * 16 + l16;
            int sw  = row & 15;
            #pragma unroll
            for (int s = 0; s < 3; ++s) {
                f16x8 bF = *(const f16x8*)(vb + row * 256 + (((s << 2) + quad) ^ sw) * 16);
                acc[nt] = __builtin_amdgcn_mfma_f32_16x16x32_f16(aF[s], bF, acc[nt], 0, 0, 0);
            }
        }
    }

    // ---- epilogue: transpose 64co x 64px through LDS, coalesced fp32 stores
    __syncthreads();
    float* vf = (float*)vlds;
    #pragma unroll
    for (int r = 0; r < 4; ++r) {
        int o = wv * 16 + quad * 4 + r;
        #pragma unroll
        for (int nt = 0; nt < 4; ++nt) {
            int col = nt ^ quad;
            vf[o * 64 + col * 16 + l16] = acc[nt][r];
        }
    }
    __syncthreads();
    float* ob = out + ((size_t)(b * 64)) * HW + hrow * 128 + ns * 64;
    #pragma unroll
    for (int it = 0; it < 4; ++it) {
        int slot = tid + it * 256;
        int o    = slot >> 4;
        int p4   = slot & 15;
        int col  = (p4 >> 2) ^ ((o >> 2) & 3);
        f32x4 v = *(const f32x4*)(vf + o * 64 + col * 16 + (p4 & 3) * 4);
        float bv = bias[o];
        float4 sv = make_float4(v[0] + bv, v[1] + bv, v[2] + bv, v[3] + bv);
        *(float4*)(ob + (size_t)o * HW + p4 * 4) = sv;
    }
}

// ---------------------------------------------------------------------------
extern "C" void kernel_launch(void* const* d_in, const int* in_sizes, int n_in,
                              void* d_out, int out_size, void* d_ws, size_t ws_size,
                              hipStream_t stream) {
    const float* x  = (const float*)d_in[0];
    const float* ef = (const float*)d_in[1];
    const float* w1 = (const float*)d_in[2];
    const float* b1 = (const float*)d_in[3];
    const float* w2 = (const float*)d_in[4];
    const float* b2 = (const float*)d_in[5];
    const float* w3 = (const float*)d_in[6];
    const float* b3 = (const float*)d_in[7];
    const float* w4 = (const float*)d_in[8];
    const float* b4 = (const float*)d_in[9];
    const float* wd = (const float*)d_in[10];
    const float* bd = (const float*)d_in[11];
    float* out = (float*)d_out;

    char* ws = (char*)d_ws;
    _Float16* ef_t = (_Float16*)(ws);                     // 25,165,824 B
    _Float16* tA   = (_Float16*)(ws + 25165824);          //  8,388,608 B
    _Float16* tB   = (_Float16*)(ws + 33554432);          //  8,388,608 B
    _Float16* off2 = (_Float16*)(ws + 41943040);          // 37,748,736 B
    _Float16* mskb = (_Float16*)(ws + 79691776);          // 18,874,368 B
    _Float16* wpd  = (_Float16*)(ws + 98566144);          //    196,608 B
    _Float16* A1   = (_Float16*)(ws + 98762752);          //    221,184 B
    _Float16* A2   = (_Float16*)(ws + 98983936);          //     73,728 B
    _Float16* A3   = (_Float16*)(ws + 99057664);          //     73,728 B
    _Float16* A4   = (_Float16*)(ws + 99131392);          //    589,824 B
    _Float16* xtb  = (_Float16*)(ws + 99721216);          // 16,777,216 B -> ends 116,498,432

    prep_all<<<6864, 256, 0, stream>>>(wd, w1, w2, w3, w4, x, ef,
                                       wpd, A1, A2, A3, A4, xtb, ef_t);

    //            CIN  COUT COpad NWM NWN MT NT ACT MINW
    conv_mfma2<192,  64,  64,  2,  2, 2, 2, 1, 4><<<dim3(1024, 1), 256, 0, stream>>>(ef_t, A1, b1, tA, nullptr);
    conv_mfma2< 64,  64,  64,  2,  2, 2, 2, 1, 4><<<dim3(1024, 1), 256, 0, stream>>>(tA, A2, b2, tB, nullptr);
    conv_mfma2< 64,  64,  64,  2,  2, 2, 2, 1, 4><<<dim3(1024, 1), 256, 0, stream>>>(tB, A3, b3, tA, nullptr);
    conv_mfma2< 64, 432, 512,  4,  1, 4, 4, 2, 3><<<dim3(1024, 2), 256, 0, stream>>>(tA, A4, b4, off2, mskb);

    deform_fused<<<1024, 256, 0, stream>>>(xtb, off2, mskb, wpd, bd, out);
}

// Round 11
// 307.675 us; speedup vs baseline: 1.0897x; 1.0289x over previous
//
#include <hip/hip_runtime.h>
#include <cstdint>

#define H_ 128
#define W_ 128
#define HW 16384

typedef _Float16 f16x8 __attribute__((ext_vector_type(8)));
typedef _Float16 f16x4 __attribute__((ext_vector_type(4)));
typedef _Float16 f16x2 __attribute__((ext_vector_type(2)));
typedef float f32x4 __attribute__((ext_vector_type(4)));

// ---------------------------------------------------------------------------
// All weight preps + x transpose in ONE launch (branch ladder on blockIdx).
// ef NCHW->NHWC transpose REMOVED: conv1 now reads ef fp32 directly in its
// stage (saves 25 MB write + ~75 MB re-read + 512 blocks here).
// ---------------------------------------------------------------------------
__global__ __launch_bounds__(256)
void prep_all(const float* __restrict__ wd, const float* __restrict__ w1,
              const float* __restrict__ w2, const float* __restrict__ w3,
              const float* __restrict__ w4, const float* __restrict__ x,
              _Float16* __restrict__ wp, _Float16* __restrict__ A1,
              _Float16* __restrict__ A2, _Float16* __restrict__ A3,
              _Float16* __restrict__ A4, _Float16* __restrict__ xt) {
    const int bx  = blockIdx.x;
    const int tid = threadIdx.x;
    if (bx < 384) {                          // deform weight -> Wp[g][o][kc96]
        int i = bx * 256 + tid;
        int kc = i % 96;
        int go = i / 96;
        int o = go & 63, g = go >> 6;
        float v = 0.f;
        if (kc < 72) { int k = kc >> 3, c = kc & 7; v = wd[(o * 128 + g * 8 + c) * 9 + k]; }
        wp[i] = (_Float16)v;
    } else if (bx < 2256) {                  // conv A layouts
        const float* w; _Float16* Ap; int CIN, COUT, COpad, base;
        if (bx < 816)       { w = w1; Ap = A1; CIN = 192; COUT = 64;  COpad = 64;  base = 384; }
        else if (bx < 960)  { w = w2; Ap = A2; CIN = 64;  COUT = 64;  COpad = 64;  base = 816; }
        else if (bx < 1104) { w = w3; Ap = A3; CIN = 64;  COUT = 64;  COpad = 64;  base = 960; }
        else                { w = w4; Ap = A4; CIN = 64;  COUT = 432; COpad = 512; base = 1104; }
        int i = (bx - base) * 256 + tid;
        int kb = i / (COpad * 8);
        int rem = i - kb * (COpad * 8);
        int co = rem >> 3, j = rem & 7;
        int k = kb * 8 + j;
        int s = k / CIN;
        int ci = k - s * CIN;
        int kh = s / 3, kw = s % 3;
        float v = (co < COUT) ? w[((size_t)co * CIN + ci) * 9 + kh * 3 + kw] : 0.f;
        Ap[i] = (_Float16)v;
    } else {                                 // x -> xt[b][g][px][c8] fp16
        int i = (bx - 2256) * 256 + tid;
        int px = i & 16383;
        int g  = (i >> 14) & 15;
        int b  = i >> 18;
        const float* xp = x + ((size_t)(b * 128 + g * 8) * HW) + px;
        f16x8 v;
        #pragma unroll
        for (int c = 0; c < 8; ++c) v[c] = (_Float16)xp[c * HW];
        *(f16x8*)(xt + (size_t)i * 8) = v;
    }
}

// ---------------------------------------------------------------------------
// MFMA implicit-GEMM 3x3 conv, pad 1. 64-px half-row tiles (25.3 KB LDS).
// STRAIGHT-LINE structure only: stage -> barrier -> compute -> epilogue,
// cout groups via blockIdx.y. conv4: MT=4/NT=4 (r8-verified).
// F32IN: input is fp32 NCHW (ef) — stage transposes+converts on the fly,
// loop ordered so lanes sweep w for a fixed channel octet (coalesced).
// ACT 1 = lrelu -> NHWC fp16. ACT 2 = conv4 epilogue (offsets+mask).
// ---------------------------------------------------------------------------
template<int CIN_T, int COUT_T, int COpad_T, int NWM, int NWN, int MT, int NT,
         int ACT, int MINW, bool F32IN>
__global__ __launch_bounds__(256, MINW)
void conv_mfma2(const void* __restrict__ inp, const _Float16* __restrict__ Ap,
                const float* __restrict__ bias, void* __restrict__ outp,
                _Float16* __restrict__ mskp) {
    constexpr int PX = 64;
    static_assert(NWM * NWN == 4 && NWN * NT * 16 == PX, "tiling");
    constexpr int TW  = PX + 2;                  // 66
    constexpr int CPC = CIN_T / 8;
    constexpr int NKH = (CIN_T == 64) ? 3 : 1;
    constexpr int NST = 3 / NKH;
    constexpr int TC  = NKH * TW * CPC;          // f16x8 chunks per stage
    constexpr int COg = NWM * MT * 16;
    __shared__ __align__(16) _Float16 lds[TC * 8];

    const int tid  = threadIdx.x;
    const int bxr  = (blockIdx.x & 7) * 128 + (blockIdx.x >> 3);
    const int ns   = bxr & 1;
    const int bh   = bxr >> 1;
    const int b    = bh >> 7;
    const int h    = bh & 127;
    const int cogB = blockIdx.y * COg;
    const int wv   = tid >> 6;
    const int wv_m = wv / NWN;
    const int wv_n = wv - wv_m * NWN;
    const int lane = tid & 63;
    const int quad = lane >> 4;
    const int l16  = lane & 15;
    const int w0g  = ns * PX;

    f32x4 acc[MT][NT];
    #pragma unroll
    for (int mt = 0; mt < MT; ++mt)
        #pragma unroll
        for (int nt = 0; nt < NT; ++nt) acc[mt][nt] = (f32x4){0.f, 0.f, 0.f, 0.f};

    const _Float16* inb = (const _Float16*)inp + (size_t)b * (HW * CIN_T);
    const float*    inF = (const float*)inp + (size_t)b * ((size_t)HW * CIN_T);

    auto stage = [&](int s) {
        if constexpr (F32IN) {
            // fp32 NCHW input; NKH==1 so kh_l==0. wp_ fastest -> coalesced.
            const int hh = h - 1 + s;
            for (int j = tid; j < TC; j += 256) {
                int c8  = j / TW;
                int wp_ = j - c8 * TW;
                int w   = w0g + wp_ - 1;
                f16x8 v = (f16x8){0, 0, 0, 0, 0, 0, 0, 0};
                if ((unsigned)hh < 128u && (unsigned)w < 128u) {
                    const float* ep = inF + ((size_t)(c8 * 8) * HW) + hh * 128 + w;
                    #pragma unroll
                    for (int c = 0; c < 8; ++c) v[c] = (_Float16)ep[(size_t)c * HW];
                }
                int slot = (c8 & ~7) | ((c8 & 7) ^ (wp_ & 7));
                ((f16x8*)lds)[wp_ * CPC + slot] = v;
            }
        } else {
            for (int i = tid; i < TC; i += 256) {
                int kh_l = i / (TW * CPC);
                int r2   = i - kh_l * (TW * CPC);
                int wp_  = r2 / CPC;
                int c8   = r2 - wp_ * CPC;
                int kh   = s * NKH + kh_l;
                int hh   = h - 1 + kh;
                int w    = w0g + wp_ - 1;
                f16x8 v = (f16x8){0, 0, 0, 0, 0, 0, 0, 0};
                if ((unsigned)hh < 128u && (unsigned)w < 128u)
                    v = *(const f16x8*)(inb + (hh * 128 + w) * CIN_T + c8 * 8);
                int slot = (c8 & ~7) | ((c8 & 7) ^ (wp_ & 7));
                ((f16x8*)lds)[(kh_l * TW + wp_) * CPC + slot] = v;
            }
        }
    };

    auto compute = [&](int s) {
        #pragma unroll
        for (int kh_l = 0; kh_l < NKH; ++kh_l) {
            const int kh = s * NKH + kh_l;
            #pragma unroll
            for (int kwi = 0; kwi < 3; ++kwi) {
                #pragma unroll
                for (int ci32 = 0; ci32 < CIN_T / 32; ++ci32) {
                    const int kb0 = (kh * 3 + kwi) * CPC + ci32 * 4;
                    f16x8 aF[MT];
                    #pragma unroll
                    for (int mt = 0; mt < MT; ++mt) {
                        int co_m = cogB + (wv_m * MT + mt) * 16 + l16;
                        aF[mt] = *(const f16x8*)(Ap + ((size_t)(kb0 + quad) * COpad_T + co_m) * 8);
                    }
                    const int c8v = ci32 * 4 + quad;
                    #pragma unroll
                    for (int nt = 0; nt < NT; ++nt) {
                        int n  = (wv_n * NT + nt) * 16 + l16;
                        int wq = n + kwi;
                        int slot = (c8v & ~7) | ((c8v & 7) ^ (wq & 7));
                        f16x8 bF = ((const f16x8*)lds)[(kh_l * TW + wq) * CPC + slot];
                        #pragma unroll
                        for (int mt = 0; mt < MT; ++mt)
                            acc[mt][nt] = __builtin_amdgcn_mfma_f32_16x16x32_f16(aF[mt], bF, acc[mt][nt], 0, 0, 0);
                    }
                }
            }
        }
    };

    #pragma unroll 1
    for (int s = 0; s < NST; ++s) {
        __syncthreads();
        stage(s);
        __syncthreads();
        compute(s);
    }

    if constexpr (ACT == 1) {
        _Float16* ob = (_Float16*)outp + ((size_t)((b * 128 + h) * 128) + w0g) * 64;
        #pragma unroll
        for (int mt = 0; mt < MT; ++mt) {
            int co_b = (wv_m * MT + mt) * 16 + quad * 4;
            #pragma unroll
            for (int nt = 0; nt < NT; ++nt) {
                int px = (wv_n * NT + nt) * 16 + l16;
                f16x4 sv;
                #pragma unroll
                for (int r = 0; r < 4; ++r) {
                    float v = acc[mt][nt][r] + bias[co_b + r];
                    v = v > 0.f ? v : 0.1f * v;
                    sv[r] = (_Float16)v;
                }
                *(f16x4*)(ob + px * 64 + co_b) = sv;
            }
        }
    } else {
        _Float16* off2 = (_Float16*)outp;
        const int pxbase = h * 128 + w0g;
        #pragma unroll
        for (int mt = 0; mt < MT; ++mt) {
            int co_base = cogB + (wv_m * MT + mt) * 16 + quad * 4;   // even
            #pragma unroll
            for (int r2 = 0; r2 < 2; ++r2) {
                int co0 = co_base + 2 * r2;
                if (co0 < 288) {             // offset pair (dy co0, dx co0+1)
                    int g = co0 / 18;
                    int k = (co0 - g * 18) >> 1;
                    float bv0 = bias[co0], bv1 = bias[co0 + 1];
                    #pragma unroll
                    for (int nt = 0; nt < NT; ++nt) {
                        int px = (wv_n * NT + nt) * 16 + l16;
                        float v0 = acc[mt][nt][2 * r2]     + bv0;
                        float v1 = acc[mt][nt][2 * r2 + 1] + bv1;
                        float e0 = __expf(2.f * v0);
                        float e1 = __expf(2.f * v1);
                        f16x2 ov;
                        ov[0] = (_Float16)(10.f * (1.f - 2.f / (e0 + 1.f)));
                        ov[1] = (_Float16)(10.f * (1.f - 2.f / (e1 + 1.f)));
                        *(f16x2*)(off2 + (((size_t)(b * 16 + g) * 9 + k) * HW + pxbase + px) * 2) = ov;
                    }
                } else if (co0 < 432) {      // two mask channels
                    #pragma unroll
                    for (int j = 0; j < 2; ++j) {
                        int co = co0 + j;
                        int mm = co - 288;
                        int g = mm / 9;
                        int k = mm - g * 9;
                        float bv = bias[co];
                        #pragma unroll
                        for (int nt = 0; nt < NT; ++nt) {
                            int px = (wv_n * NT + nt) * 16 + l16;
                            float v = acc[mt][nt][2 * r2 + j] + bv;
                            v = 1.f / (1.f + __expf(-v));
                            mskp[((size_t)(b * 16 + g) * 9 + k) * HW + pxbase + px] = (_Float16)v;
                        }
                    }
                }
            }
        }
    }
}

// ---------------------------------------------------------------------------
// FUSED deformable conv — exact r8 version (best measured: 74.5 us,
// 0 bank conflicts). Direct-global issue-all/finish-all gathers; at the
// scattered-request TA floor (~61 us); r9/r10 alternatives both regressed.
// ---------------------------------------------------------------------------
__global__ __launch_bounds__(256, 4)
void deform_fused(const _Float16* __restrict__ xt, const _Float16* __restrict__ off2,
                  const _Float16* __restrict__ msk, const _Float16* __restrict__ wp,
                  const float* __restrict__ bias, float* __restrict__ out) {
    __shared__ __align__(16) char vlds[2 * 64 * 256];   // 32 KB, double-buffered
    const int tid  = threadIdx.x;
    const int bx   = (blockIdx.x & 7) * 128 + (blockIdx.x >> 3);
    const int ns   = bx & 1;
    const int bh   = bx >> 1;
    const int b    = bh >> 7;
    const int hrow = bh & 127;
    const int wv   = tid >> 6;
    const int lane = tid & 63;
    const int quad = lane >> 4;
    const int l16  = lane & 15;

    const int pxl   = tid & 63;        // local px (V row)
    const int kq    = tid >> 6;        // k-quarter (wave-uniform)
    const int wglob = ns * 64 + pxl;
    const int pxg   = hrow * 128 + wglob;

    {   // zero both buffers: swizzled chunks (9..11)^sw are never written
        f32x4 z = (f32x4){0.f, 0.f, 0.f, 0.f};
        for (int i = tid; i < 2048; i += 256) ((f32x4*)vlds)[i] = z;
    }
    __syncthreads();

    const _Float16* o2b = off2 + (size_t)b * 16 * 9 * HW * 2;
    const _Float16* mb  = msk  + (size_t)b * 16 * 9 * HW;

    f32x4 acc[4];
    #pragma unroll
    for (int nt = 0; nt < 4; ++nt) acc[nt] = (f32x4){0.f, 0.f, 0.f, 0.f};

    // LDS chunk byte offsets are group-invariant
    int ch[3];
    #pragma unroll
    for (int i = 0; i < 3; ++i) ch[i] = (((kq + 4 * i) ^ (pxl & 15)) << 4);

    // in-flight gather state (3 taps x 4 corners)
    f16x8 g00[3], g01[3], g10[3], g11[3];
    _Float16 h00[3], h01[3], h10[3], h11[3];

    // issue: compute all tap addrs+weights, fire all loads (no consumers here)
    auto issue = [&](int gl, const f16x2* od, const _Float16* m) {
        const _Float16* xg = xt + ((size_t)(b * 16 + gl) * HW) * 8;
        #pragma unroll
        for (int i = 0; i < 3; ++i) {
            int k = kq + 4 * i;
            if (k < 9) {
                float dy = (float)od[i][0];
                float dx = (float)od[i][1];
                float mm = (float)m[i];
                float py  = (float)(hrow - 1 + k / 3) + dy;
                float pxf = (float)(wglob - 1 + k % 3) + dx;
                float y0f = floorf(py), x0f = floorf(pxf);
                float ly = py - y0f, lx = pxf - x0f;
                int y0 = (int)y0f, x0 = (int)x0f;
                int y1 = y0 + 1,  x1 = x0 + 1;
                float vy0 = ((unsigned)y0 < 128u) ? 1.f : 0.f;
                float vy1 = ((unsigned)y1 < 128u) ? 1.f : 0.f;
                float vx0 = ((unsigned)x0 < 128u) ? 1.f : 0.f;
                float vx1 = ((unsigned)x1 < 128u) ? 1.f : 0.f;
                h00[i] = (_Float16)((1.f - ly) * (1.f - lx) * vy0 * vx0 * mm);
                h01[i] = (_Float16)((1.f - ly) * lx         * vy0 * vx1 * mm);
                h10[i] = (_Float16)(ly * (1.f - lx)         * vy1 * vx0 * mm);
                h11[i] = (_Float16)(ly * lx                 * vy1 * vx1 * mm);
                int yc0 = min(max(y0, 0), 127), yc1 = min(max(y1, 0), 127);
                int xc0 = min(max(x0, 0), 127), xc1 = min(max(x1, 0), 127);
                g00[i] = *(const f16x8*)(xg + (yc0 * W_ + xc0) * 8);
                g01[i] = *(const f16x8*)(xg + (yc0 * W_ + xc1) * 8);
                g10[i] = *(const f16x8*)(xg + (yc1 * W_ + xc0) * 8);
                g11[i] = *(const f16x8*)(xg + (yc1 * W_ + xc1) * 8);
            }
        }
    };

    // finish: lerp all taps, write V tile
    auto finish = [&](int gl) {
        char* vb = vlds + (gl & 1) * 16384;
        #pragma unroll
        for (int i = 0; i < 3; ++i) {
            int k = kq + 4 * i;
            if (k < 9) {
                f16x8 vv = g00[i] * h00[i] + g01[i] * h01[i]
                         + g10[i] * h10[i] + g11[i] * h11[i];   // v_pk_fma_f16
                *(f16x8*)(vb + pxl * 256 + ch[i]) = vv;
            }
        }
    };

    // prologue: offsets + gathers for group 0
    {
        f16x2 od0[3]; _Float16 m0[3];
        #pragma unroll
        for (int i = 0; i < 3; ++i) {
            od0[i] = (f16x2){0, 0}; m0[i] = (_Float16)0.f;
            int k = kq + 4 * i;
            if (k < 9) {
                od0[i] = *(const f16x2*)(o2b + ((size_t)k * HW + pxg) * 2);
                m0[i]  = mb[(size_t)k * HW + pxg];
            }
        }
        issue(0, od0, m0);
    }

    #pragma unroll 1
    for (int gl = 0; gl < 16; ++gl) {
        // prefetch offsets/masks for gl+1 (independent; long latency OK)
        f16x2 od_n[3]; _Float16 m_n[3];
        #pragma unroll
        for (int i = 0; i < 3; ++i) { od_n[i] = (f16x2){0, 0}; m_n[i] = (_Float16)0.f; }
        if (gl < 15) {
            #pragma unroll
            for (int i = 0; i < 3; ++i) {
                int k = kq + 4 * i;
                if (k < 9) {
                    od_n[i] = *(const f16x2*)(o2b + ((size_t)((gl + 1) * 9 + k) * HW + pxg) * 2);
                    m_n[i]  = mb[(size_t)((gl + 1) * 9 + k) * HW + pxg];
                }
            }
        }

        // weight fragments for this group (L2-resident) — r8 layout
        f16x8 aF[3];
        const _Float16* wg = wp + ((size_t)(gl * 64 + wv * 16 + l16)) * 96 + quad * 8;
        #pragma unroll
        for (int s = 0; s < 3; ++s) aF[s] = *(const f16x8*)(wg + s * 32);

        finish(gl);                    // wait gathers, lerp, write vb[gl&1]
        __syncthreads();

        if (gl < 15) issue(gl + 1, od_n, m_n);   // loads fly during MFMA

        char* vb = vlds + (gl & 1) * 16384;
        #pragma unroll
        for (int nt = 0; nt < 4; ++nt) {
            int row = nt * 16 + l16;
            int sw  = row & 15;
            #pragma unroll
            for (int s = 0; s < 3; ++s) {
                f16x8 bF = *(const f16x8*)(vb + row * 256 + (((s << 2) + quad) ^ sw) * 16);
                acc[nt] = __builtin_amdgcn_mfma_f32_16x16x32_f16(aF[s], bF, acc[nt], 0, 0, 0);
            }
        }
    }

    // ---- epilogue: transpose 64co x 64px through LDS, coalesced fp32 stores
    __syncthreads();
    float* vf = (float*)vlds;
    #pragma unroll
    for (int r = 0; r < 4; ++r) {
        int o = wv * 16 + quad * 4 + r;
        #pragma unroll
        for (int nt = 0; nt < 4; ++nt) {
            int col = nt ^ quad;
            vf[o * 64 + col * 16 + l16] = acc[nt][r];
        }
    }
    __syncthreads();
    float* ob = out + ((size_t)(b * 64)) * HW + hrow * 128 + ns * 64;
    #pragma unroll
    for (int it = 0; it < 4; ++it) {
        int slot = tid + it * 256;
        int o    = slot >> 4;
        int p4   = slot & 15;
        int col  = (p4 >> 2) ^ ((o >> 2) & 3);
        f32x4 v = *(const f32x4*)(vf + o * 64 + col * 16 + (p4 & 3) * 4);
        float bv = bias[o];
        float4 sv = make_float4(v[0] + bv, v[1] + bv, v[2] + bv, v[3] + bv);
        *(float4*)(ob + (size_t)o * HW + p4 * 4) = sv;
    }
}

// ---------------------------------------------------------------------------
extern "C" void kernel_launch(void* const* d_in, const int* in_sizes, int n_in,
                              void* d_out, int out_size, void* d_ws, size_t ws_size,
                              hipStream_t stream) {
    const float* x  = (const float*)d_in[0];
    const float* ef = (const float*)d_in[1];
    const float* w1 = (const float*)d_in[2];
    const float* b1 = (const float*)d_in[3];
    const float* w2 = (const float*)d_in[4];
    const float* b2 = (const float*)d_in[5];
    const float* w3 = (const float*)d_in[6];
    const float* b3 = (const float*)d_in[7];
    const float* w4 = (const float*)d_in[8];
    const float* b4 = (const float*)d_in[9];
    const float* wd = (const float*)d_in[10];
    const float* bd = (const float*)d_in[11];
    float* out = (float*)d_out;

    char* ws = (char*)d_ws;
    _Float16* tA   = (_Float16*)(ws + 25165824);          //  8,388,608 B
    _Float16* tB   = (_Float16*)(ws + 33554432);          //  8,388,608 B
    _Float16* off2 = (_Float16*)(ws + 41943040);          // 37,748,736 B
    _Float16* mskb = (_Float16*)(ws + 79691776);          // 18,874,368 B
    _Float16* wpd  = (_Float16*)(ws + 98566144);          //    196,608 B
    _Float16* A1   = (_Float16*)(ws + 98762752);          //    221,184 B
    _Float16* A2   = (_Float16*)(ws + 98983936);          //     73,728 B
    _Float16* A3   = (_Float16*)(ws + 99057664);          //     73,728 B
    _Float16* A4   = (_Float16*)(ws + 99131392);          //    589,824 B
    _Float16* xtb  = (_Float16*)(ws + 99721216);          // 16,777,216 B

    prep_all<<<6352, 256, 0, stream>>>(wd, w1, w2, w3, w4, x,
                                       wpd, A1, A2, A3, A4, xtb);

    //            CIN  COUT COpad NWM NWN MT NT ACT MINW F32IN
    conv_mfma2<192,  64,  64,  2,  2, 2, 2, 1, 4, true ><<<dim3(1024, 1), 256, 0, stream>>>(ef, A1, b1, tA, nullptr);
    conv_mfma2< 64,  64,  64,  2,  2, 2, 2, 1, 4, false><<<dim3(1024, 1), 256, 0, stream>>>(tA, A2, b2, tB, nullptr);
    conv_mfma2< 64,  64,  64,  2,  2, 2, 2, 1, 4, false><<<dim3(1024, 1), 256, 0, stream>>>(tB, A3, b3, tA, nullptr);
    conv_mfma2< 64, 432, 512,  4,  1, 4, 4, 2, 2, false><<<dim3(1024, 2), 256, 0, stream>>>(tA, A4, b4, off2, mskb);

    deform_fused<<<1024, 256, 0, stream>>>(xtb, off2, mskb, wpd, bd, out);
}

// Round 12
// 307.233 us; speedup vs baseline: 1.0913x; 1.0014x over previous
//
#include <hip/hip_runtime.h>
#include <cstdint>

#define H_ 128
#define W_ 128
#define HW 16384

typedef _Float16 f16x8 __attribute__((ext_vector_type(8)));
typedef _Float16 f16x4 __attribute__((ext_vector_type(4)));
typedef _Float16 f16x2 __attribute__((ext_vector_type(2)));
typedef float f32x4 __attribute__((ext_vector_type(4)));

// ---------------------------------------------------------------------------
// All weight preps + x transpose in ONE launch (branch ladder on blockIdx).
// ---------------------------------------------------------------------------
__global__ __launch_bounds__(256)
void prep_all(const float* __restrict__ wd, const float* __restrict__ w1,
              const float* __restrict__ w2, const float* __restrict__ w3,
              const float* __restrict__ w4, const float* __restrict__ x,
              _Float16* __restrict__ wp, _Float16* __restrict__ A1,
              _Float16* __restrict__ A2, _Float16* __restrict__ A3,
              _Float16* __restrict__ A4, _Float16* __restrict__ xt) {
    const int bx  = blockIdx.x;
    const int tid = threadIdx.x;
    if (bx < 384) {                          // deform weight -> Wp[g][o][kc96]
        int i = bx * 256 + tid;
        int kc = i % 96;
        int go = i / 96;
        int o = go & 63, g = go >> 6;
        float v = 0.f;
        if (kc < 72) { int k = kc >> 3, c = kc & 7; v = wd[(o * 128 + g * 8 + c) * 9 + k]; }
        wp[i] = (_Float16)v;
    } else if (bx < 2256) {                  // conv A layouts
        const float* w; _Float16* Ap; int CIN, COUT, COpad, base;
        if (bx < 816)       { w = w1; Ap = A1; CIN = 192; COUT = 64;  COpad = 64;  base = 384; }
        else if (bx < 960)  { w = w2; Ap = A2; CIN = 64;  COUT = 64;  COpad = 64;  base = 816; }
        else if (bx < 1104) { w = w3; Ap = A3; CIN = 64;  COUT = 64;  COpad = 64;  base = 960; }
        else                { w = w4; Ap = A4; CIN = 64;  COUT = 432; COpad = 512; base = 1104; }
        int i = (bx - base) * 256 + tid;
        int kb = i / (COpad * 8);
        int rem = i - kb * (COpad * 8);
        int co = rem >> 3, j = rem & 7;
        int k = kb * 8 + j;
        int s = k / CIN;
        int ci = k - s * CIN;
        int kh = s / 3, kw = s % 3;
        float v = (co < COUT) ? w[((size_t)co * CIN + ci) * 9 + kh * 3 + kw] : 0.f;
        Ap[i] = (_Float16)v;
    } else {                                 // x -> xt[b][g][px][c8] fp16
        int i = (bx - 2256) * 256 + tid;
        int px = i & 16383;
        int g  = (i >> 14) & 15;
        int b  = i >> 18;
        const float* xp = x + ((size_t)(b * 128 + g * 8) * HW) + px;
        f16x8 v;
        #pragma unroll
        for (int c = 0; c < 8; ++c) v[c] = (_Float16)xp[c * HW];
        *(f16x8*)(xt + (size_t)i * 8) = v;
    }
}

// ---------------------------------------------------------------------------
// MFMA implicit-GEMM 3x3 conv, pad 1. ROWS output rows x 64-px half-row per
// block. STRAIGHT-LINE: stage -> barrier -> compute -> epilogue, cout groups
// via blockIdx.y. ROWS=2 (conv2/3): stage ROWS+2=4 rows for 2 output rows
// (halo overstage 3.1x -> 2x) and NT=4 so each aF pair feeds 8 MFMAs (the
// r7->r8 conv4 lever). conv4: MT=4/NT=4 ROWS=1 (r8-verified).
// F32IN: fp32 NCHW input (ef), transpose+convert in stage (coalesced).
// ACT 1 = lrelu -> NHWC fp16. ACT 2 = conv4 epilogue (offsets+mask).
// ---------------------------------------------------------------------------
template<int CIN_T, int COUT_T, int COpad_T, int NWM, int NWN, int MT, int NT,
         int ACT, int MINW, bool F32IN, int ROWS>
__global__ __launch_bounds__(256, MINW)
void conv_mfma2(const void* __restrict__ inp, const _Float16* __restrict__ Ap,
                const float* __restrict__ bias, void* __restrict__ outp,
                _Float16* __restrict__ mskp) {
    constexpr int PX = 64;
    static_assert(NWM * NWN == 4 && NWN * NT * 16 == PX * ROWS, "tiling");
    constexpr int TW  = PX + 2;                  // 66
    constexpr int CPC = CIN_T / 8;
    constexpr int NKH = (CIN_T == 64) ? 3 : 1;
    constexpr int NST = 3 / NKH;
    static_assert(ROWS == 1 || NKH == 3, "multi-row needs single-stage path");
    constexpr int SR  = (CIN_T == 64) ? (ROWS + 2) : 1;  // staged rows/call
    constexpr int TC  = SR * TW * CPC;           // f16x8 chunks per stage
    constexpr int COg = NWM * MT * 16;
    constexpr int NBLK = 1024 / ROWS;            // grid.x
    constexpr int CPX  = NBLK / 8;               // blocks per XCD
    constexpr int HB   = 128 / ROWS;             // row-tiles per image
    __shared__ __align__(16) _Float16 lds[TC * 8];

    const int tid  = threadIdx.x;
    const int bxr  = (blockIdx.x & 7) * CPX + (blockIdx.x >> 3);
    const int ns   = bxr & 1;
    const int bh   = bxr >> 1;
    const int b    = bh / HB;
    const int h0   = (bh % HB) * ROWS;
    const int cogB = blockIdx.y * COg;
    const int wv   = tid >> 6;
    const int wv_m = wv / NWN;
    const int wv_n = wv - wv_m * NWN;
    const int lane = tid & 63;
    const int quad = lane >> 4;
    const int l16  = lane & 15;
    const int w0g  = ns * PX;

    f32x4 acc[MT][NT];
    #pragma unroll
    for (int mt = 0; mt < MT; ++mt)
        #pragma unroll
        for (int nt = 0; nt < NT; ++nt) acc[mt][nt] = (f32x4){0.f, 0.f, 0.f, 0.f};

    const _Float16* inb = (const _Float16*)inp + (size_t)b * (HW * CIN_T);
    const float*    inF = (const float*)inp + (size_t)b * ((size_t)HW * CIN_T);

    auto stage = [&](int s) {
        if constexpr (F32IN) {
            // fp32 NCHW input; SR==1. wp_ fastest -> coalesced.
            const int hh = h0 - 1 + s;
            for (int j = tid; j < TC; j += 256) {
                int c8  = j / TW;
                int wp_ = j - c8 * TW;
                int w   = w0g + wp_ - 1;
                f16x8 v = (f16x8){0, 0, 0, 0, 0, 0, 0, 0};
                if ((unsigned)hh < 128u && (unsigned)w < 128u) {
                    const float* ep = inF + ((size_t)(c8 * 8) * HW) + hh * 128 + w;
                    #pragma unroll
                    for (int c = 0; c < 8; ++c) v[c] = (_Float16)ep[(size_t)c * HW];
                }
                int slot = (c8 & ~7) | ((c8 & 7) ^ (wp_ & 7));
                ((f16x8*)lds)[wp_ * CPC + slot] = v;
            }
        } else {
            for (int i = tid; i < TC; i += 256) {
                int row_l = i / (TW * CPC);
                int r2    = i - row_l * (TW * CPC);
                int wp_   = r2 / CPC;
                int c8    = r2 - wp_ * CPC;
                int hh    = h0 - 1 + s * SR + row_l;   // SR rows from h0-1
                int w     = w0g + wp_ - 1;
                f16x8 v = (f16x8){0, 0, 0, 0, 0, 0, 0, 0};
                if ((unsigned)hh < 128u && (unsigned)w < 128u)
                    v = *(const f16x8*)(inb + (hh * 128 + w) * CIN_T + c8 * 8);
                int slot = (c8 & ~7) | ((c8 & 7) ^ (wp_ & 7));
                ((f16x8*)lds)[(row_l * TW + wp_) * CPC + slot] = v;
            }
        }
    };

    auto compute = [&](int s) {
        #pragma unroll
        for (int kh_l = 0; kh_l < NKH; ++kh_l) {
            const int kh = s * NKH + kh_l;
            #pragma unroll
            for (int kwi = 0; kwi < 3; ++kwi) {
                #pragma unroll
                for (int ci32 = 0; ci32 < CIN_T / 32; ++ci32) {
                    const int kb0 = (kh * 3 + kwi) * CPC + ci32 * 4;
                    f16x8 aF[MT];
                    #pragma unroll
                    for (int mt = 0; mt < MT; ++mt) {
                        int co_m = cogB + (wv_m * MT + mt) * 16 + l16;
                        aF[mt] = *(const f16x8*)(Ap + ((size_t)(kb0 + quad) * COpad_T + co_m) * 8);
                    }
                    const int c8v = ci32 * 4 + quad;
                    #pragma unroll
                    for (int nt = 0; nt < NT; ++nt) {
                        int n  = (wv_n * NT + nt) * 16 + l16;
                        int row_sel = n >> 6;          // 0..ROWS-1 (0 if ROWS==1)
                        int px = n & 63;
                        int wq = px + kwi;
                        int slot = (c8v & ~7) | ((c8v & 7) ^ (wq & 7));
                        f16x8 bF = ((const f16x8*)lds)[((row_sel + kh_l) * TW + wq) * CPC + slot];
                        #pragma unroll
                        for (int mt = 0; mt < MT; ++mt)
                            acc[mt][nt] = __builtin_amdgcn_mfma_f32_16x16x32_f16(aF[mt], bF, acc[mt][nt], 0, 0, 0);
                    }
                }
            }
        }
    };

    #pragma unroll 1
    for (int s = 0; s < NST; ++s) {
        __syncthreads();
        stage(s);
        __syncthreads();
        compute(s);
    }

    if constexpr (ACT == 1) {
        _Float16* ob = (_Float16*)outp + ((size_t)((b * 128 + h0) * 128) + w0g) * 64;
        #pragma unroll
        for (int mt = 0; mt < MT; ++mt) {
            int co_b = (wv_m * MT + mt) * 16 + quad * 4;
            #pragma unroll
            for (int nt = 0; nt < NT; ++nt) {
                int n  = (wv_n * NT + nt) * 16 + l16;
                int row_sel = n >> 6;
                int px = n & 63;
                f16x4 sv;
                #pragma unroll
                for (int r = 0; r < 4; ++r) {
                    float v = acc[mt][nt][r] + bias[co_b + r];
                    v = v > 0.f ? v : 0.1f * v;
                    sv[r] = (_Float16)v;
                }
                *(f16x4*)(ob + ((size_t)row_sel * 128 + px) * 64 + co_b) = sv;
            }
        }
    } else {
        _Float16* off2 = (_Float16*)outp;
        const int pxbase = h0 * 128 + w0g;
        #pragma unroll
        for (int mt = 0; mt < MT; ++mt) {
            int co_base = cogB + (wv_m * MT + mt) * 16 + quad * 4;   // even
            #pragma unroll
            for (int r2 = 0; r2 < 2; ++r2) {
                int co0 = co_base + 2 * r2;
                if (co0 < 288) {             // offset pair (dy co0, dx co0+1)
                    int g = co0 / 18;
                    int k = (co0 - g * 18) >> 1;
                    float bv0 = bias[co0], bv1 = bias[co0 + 1];
                    #pragma unroll
                    for (int nt = 0; nt < NT; ++nt) {
                        int px = (wv_n * NT + nt) * 16 + l16;
                        float v0 = acc[mt][nt][2 * r2]     + bv0;
                        float v1 = acc[mt][nt][2 * r2 + 1] + bv1;
                        float e0 = __expf(2.f * v0);
                        float e1 = __expf(2.f * v1);
                        f16x2 ov;
                        ov[0] = (_Float16)(10.f * (1.f - 2.f / (e0 + 1.f)));
                        ov[1] = (_Float16)(10.f * (1.f - 2.f / (e1 + 1.f)));
                        *(f16x2*)(off2 + (((size_t)(b * 16 + g) * 9 + k) * HW + pxbase + px) * 2) = ov;
                    }
                } else if (co0 < 432) {      // two mask channels
                    #pragma unroll
                    for (int j = 0; j < 2; ++j) {
                        int co = co0 + j;
                        int mm = co - 288;
                        int g = mm / 9;
                        int k = mm - g * 9;
                        float bv = bias[co];
                        #pragma unroll
                        for (int nt = 0; nt < NT; ++nt) {
                            int px = (wv_n * NT + nt) * 16 + l16;
                            float v = acc[mt][nt][2 * r2 + j] + bv;
                            v = 1.f / (1.f + __expf(-v));
                            mskp[((size_t)(b * 16 + g) * 9 + k) * HW + pxbase + px] = (_Float16)v;
                        }
                    }
                }
            }
        }
    }
}

// ---------------------------------------------------------------------------
// FUSED deformable conv — exact r8 version (best measured: 74.5 us,
// 0 bank conflicts). At the scattered-request TA floor.
// ---------------------------------------------------------------------------
__global__ __launch_bounds__(256, 4)
void deform_fused(const _Float16* __restrict__ xt, const _Float16* __restrict__ off2,
                  const _Float16* __restrict__ msk, const _Float16* __restrict__ wp,
                  const float* __restrict__ bias, float* __restrict__ out) {
    __shared__ __align__(16) char vlds[2 * 64 * 256];   // 32 KB, double-buffered
    const int tid  = threadIdx.x;
    const int bx   = (blockIdx.x & 7) * 128 + (blockIdx.x >> 3);
    const int ns   = bx & 1;
    const int bh   = bx >> 1;
    const int b    = bh >> 7;
    const int hrow = bh & 127;
    const int wv   = tid >> 6;
    const int lane = tid & 63;
    const int quad = lane >> 4;
    const int l16  = lane & 15;

    const int pxl   = tid & 63;        // local px (V row)
    const int kq    = tid >> 6;        // k-quarter (wave-uniform)
    const int wglob = ns * 64 + pxl;
    const int pxg   = hrow * 128 + wglob;

    {   // zero both buffers: swizzled chunks (9..11)^sw are never written
        f32x4 z = (f32x4){0.f, 0.f, 0.f, 0.f};
        for (int i = tid; i < 2048; i += 256) ((f32x4*)vlds)[i] = z;
    }
    __syncthreads();

    const _Float16* o2b = off2 + (size_t)b * 16 * 9 * HW * 2;
    const _Float16* mb  = msk  + (size_t)b * 16 * 9 * HW;

    f32x4 acc[4];
    #pragma unroll
    for (int nt = 0; nt < 4; ++nt) acc[nt] = (f32x4){0.f, 0.f, 0.f, 0.f};

    int ch[3];
    #pragma unroll
    for (int i = 0; i < 3; ++i) ch[i] = (((kq + 4 * i) ^ (pxl & 15)) << 4);

    f16x8 g00[3], g01[3], g10[3], g11[3];
    _Float16 h00[3], h01[3], h10[3], h11[3];

    auto issue = [&](int gl, const f16x2* od, const _Float16* m) {
        const _Float16* xg = xt + ((size_t)(b * 16 + gl) * HW) * 8;
        #pragma unroll
        for (int i = 0; i < 3; ++i) {
            int k = kq + 4 * i;
            if (k < 9) {
                float dy = (float)od[i][0];
                float dx = (float)od[i][1];
                float mm = (float)m[i];
                float py  = (float)(hrow - 1 + k / 3) + dy;
                float pxf = (float)(wglob - 1 + k % 3) + dx;
                float y0f = floorf(py), x0f = floorf(pxf);
                float ly = py - y0f, lx = pxf - x0f;
                int y0 = (int)y0f, x0 = (int)x0f;
                int y1 = y0 + 1,  x1 = x0 + 1;
                float vy0 = ((unsigned)y0 < 128u) ? 1.f : 0.f;
                float vy1 = ((unsigned)y1 < 128u) ? 1.f : 0.f;
                float vx0 = ((unsigned)x0 < 128u) ? 1.f : 0.f;
                float vx1 = ((unsigned)x1 < 128u) ? 1.f : 0.f;
                h00[i] = (_Float16)((1.f - ly) * (1.f - lx) * vy0 * vx0 * mm);
                h01[i] = (_Float16)((1.f - ly) * lx         * vy0 * vx1 * mm);
                h10[i] = (_Float16)(ly * (1.f - lx)         * vy1 * vx0 * mm);
                h11[i] = (_Float16)(ly * lx                 * vy1 * vx1 * mm);
                int yc0 = min(max(y0, 0), 127), yc1 = min(max(y1, 0), 127);
                int xc0 = min(max(x0, 0), 127), xc1 = min(max(x1, 0), 127);
                g00[i] = *(const f16x8*)(xg + (yc0 * W_ + xc0) * 8);
                g01[i] = *(const f16x8*)(xg + (yc0 * W_ + xc1) * 8);
                g10[i] = *(const f16x8*)(xg + (yc1 * W_ + xc0) * 8);
                g11[i] = *(const f16x8*)(xg + (yc1 * W_ + xc1) * 8);
            }
        }
    };

    auto finish = [&](int gl) {
        char* vb = vlds + (gl & 1) * 16384;
        #pragma unroll
        for (int i = 0; i < 3; ++i) {
            int k = kq + 4 * i;
            if (k < 9) {
                f16x8 vv = g00[i] * h00[i] + g01[i] * h01[i]
                         + g10[i] * h10[i] + g11[i] * h11[i];   // v_pk_fma_f16
                *(f16x8*)(vb + pxl * 256 + ch[i]) = vv;
            }
        }
    };

    {
        f16x2 od0[3]; _Float16 m0[3];
        #pragma unroll
        for (int i = 0; i < 3; ++i) {
            od0[i] = (f16x2){0, 0}; m0[i] = (_Float16)0.f;
            int k = kq + 4 * i;
            if (k < 9) {
                od0[i] = *(const f16x2*)(o2b + ((size_t)k * HW + pxg) * 2);
                m0[i]  = mb[(size_t)k * HW + pxg];
            }
        }
        issue(0, od0, m0);
    }

    #pragma unroll 1
    for (int gl = 0; gl < 16; ++gl) {
        f16x2 od_n[3]; _Float16 m_n[3];
        #pragma unroll
        for (int i = 0; i < 3; ++i) { od_n[i] = (f16x2){0, 0}; m_n[i] = (_Float16)0.f; }
        if (gl < 15) {
            #pragma unroll
            for (int i = 0; i < 3; ++i) {
                int k = kq + 4 * i;
                if (k < 9) {
                    od_n[i] = *(const f16x2*)(o2b + ((size_t)((gl + 1) * 9 + k) * HW + pxg) * 2);
                    m_n[i]  = mb[(size_t)((gl + 1) * 9 + k) * HW + pxg];
                }
            }
        }

        f16x8 aF[3];
        const _Float16* wg = wp + ((size_t)(gl * 64 + wv * 16 + l16)) * 96 + quad * 8;
        #pragma unroll
        for (int s = 0; s < 3; ++s) aF[s] = *(const f16x8*)(wg + s * 32);

        finish(gl);
        __syncthreads();

        if (gl < 15) issue(gl + 1, od_n, m_n);

        char* vb = vlds + (gl & 1) * 16384;
        #pragma unroll
        for (int nt = 0; nt < 4; ++nt) {
            int row = nt * 16 + l16;
            int sw  = row & 15;
            #pragma unroll
            for (int s = 0; s < 3; ++s) {
                f16x8 bF = *(const f16x8*)(vb + row * 256 + (((s << 2) + quad) ^ sw) * 16);
                acc[nt] = __builtin_amdgcn_mfma_f32_16x16x32_f16(aF[s], bF, acc[nt], 0, 0, 0);
            }
        }
    }

    __syncthreads();
    float* vf = (float*)vlds;
    #pragma unroll
    for (int r = 0; r < 4; ++r) {
        int o = wv * 16 + quad * 4 + r;
        #pragma unroll
        for (int nt = 0; nt < 4; ++nt) {
            int col = nt ^ quad;
            vf[o * 64 + col * 16 + l16] = acc[nt][r];
        }
    }
    __syncthreads();
    float* ob = out + ((size_t)(b * 64)) * HW + hrow * 128 + ns * 64;
    #pragma unroll
    for (int it = 0; it < 4; ++it) {
        int slot = tid + it * 256;
        int o    = slot >> 4;
        int p4   = slot & 15;
        int col  = (p4 >> 2) ^ ((o >> 2) & 3);
        f32x4 v = *(const f32x4*)(vf + o * 64 + col * 16 + (p4 & 3) * 4);
        float bv = bias[o];
        float4 sv = make_float4(v[0] + bv, v[1] + bv, v[2] + bv, v[3] + bv);
        *(float4*)(ob + (size_t)o * HW + p4 * 4) = sv;
    }
}

// ---------------------------------------------------------------------------
extern "C" void kernel_launch(void* const* d_in, const int* in_sizes, int n_in,
                              void* d_out, int out_size, void* d_ws, size_t ws_size,
                              hipStream_t stream) {
    const float* x  = (const float*)d_in[0];
    const float* ef = (const float*)d_in[1];
    const float* w1 = (const float*)d_in[2];
    const float* b1 = (const float*)d_in[3];
    const float* w2 = (const float*)d_in[4];
    const float* b2 = (const float*)d_in[5];
    const float* w3 = (const float*)d_in[6];
    const float* b3 = (const float*)d_in[7];
    const float* w4 = (const float*)d_in[8];
    const float* b4 = (const float*)d_in[9];
    const float* wd = (const float*)d_in[10];
    const float* bd = (const float*)d_in[11];
    float* out = (float*)d_out;

    char* ws = (char*)d_ws;
    _Float16* tA   = (_Float16*)(ws + 25165824);          //  8,388,608 B
    _Float16* tB   = (_Float16*)(ws + 33554432);          //  8,388,608 B
    _Float16* off2 = (_Float16*)(ws + 41943040);          // 37,748,736 B
    _Float16* mskb = (_Float16*)(ws + 79691776);          // 18,874,368 B
    _Float16* wpd  = (_Float16*)(ws + 98566144);          //    196,608 B
    _Float16* A1   = (_Float16*)(ws + 98762752);          //    221,184 B
    _Float16* A2   = (_Float16*)(ws + 98983936);          //     73,728 B
    _Float16* A3   = (_Float16*)(ws + 99057664);          //     73,728 B
    _Float16* A4   = (_Float16*)(ws + 99131392);          //    589,824 B
    _Float16* xtb  = (_Float16*)(ws + 99721216);          // 16,777,216 B

    prep_all<<<6352, 256, 0, stream>>>(wd, w1, w2, w3, w4, x,
                                       wpd, A1, A2, A3, A4, xtb);

    //            CIN  COUT COpad NWM NWN MT NT ACT MINW F32IN ROWS
    conv_mfma2<192,  64,  64,  2,  2, 2, 2, 1, 4, true , 1><<<dim3(1024, 1), 256, 0, stream>>>(ef, A1, b1, tA, nullptr);
    conv_mfma2< 64,  64,  64,  2,  2, 2, 4, 1, 2, false, 2><<<dim3( 512, 1), 256, 0, stream>>>(tA, A2, b2, tB, nullptr);
    conv_mfma2< 64,  64,  64,  2,  2, 2, 4, 1, 2, false, 2><<<dim3( 512, 1), 256, 0, stream>>>(tB, A3, b3, tA, nullptr);
    conv_mfma2< 64, 432, 512,  4,  1, 4, 4, 2, 2, false, 1><<<dim3(1024, 2), 256, 0, stream>>>(tA, A4, b4, off2, mskb);

    deform_fused<<<1024, 256, 0, stream>>>(xtb, off2, mskb, wpd, bd, out);
}